// Round 10
// baseline (256.295 us; speedup 1.0000x reference)
//
#include <hip/hip_runtime.h>
#include <math.h>

// ---------------- static problem structure (LMAX=4, taus=16) ----------------
#define NTRI 42
#define NCH  10752
#define B_SZ 256
#define PART_TOT 942080      // sum over l: 256*NT*16*NM (float2), ~7.5 MB

// triples sorted by (l,l1,l2); CT_T = tile index within degree l
constexpr int CT_L [NTRI]={0,0,0,0,0, 1,1,1,1,1,1,1,1, 2,2,2,2,2,2,2,2,2,2, 3,3,3,3,3,3,3,3,3,3, 4,4,4,4,4,4,4,4,4};
constexpr int CT_L1[NTRI]={0,1,2,3,4, 1,1,2,2,3,3,4,4, 1,2,2,2,3,3,3,4,4,4, 2,2,3,3,3,3,4,4,4,4, 2,3,3,3,4,4,4,4,4};
constexpr int CT_L2[NTRI]={0,1,2,3,4, 0,1,1,2,2,3,3,4, 1,0,1,2,1,2,3,2,3,4, 1,2,0,1,2,3,1,2,3,4, 2,1,2,3,0,1,2,3,4};
constexpr int CT_T [NTRI]={0,1,2,3,4, 0,1,2,3,4,5,6,7, 0,1,2,3,4,5,6,7,8,9, 0,1,2,3,4,5,6,7,8,9, 0,1,2,3,4,5,6,7,8};

constexpr int KL_t[5]    ={1280,2048,2560,2560,2304};   // t_FF[l]
constexpr int GBASE_t[5] ={0,1280,3328,5888,8448};      // channel base
constexpr int ROFF_t[5]  ={0,16,64,144,256};            // row offset in 400-row layout
constexpr int WOFF_t[5]  ={0,20480,53248,94208,135168}; // complex offset into W
// partials: g_part[PBASE[l] + b*PSTR[l] + T*16*NM + o*NM + m]
constexpr int PSTR_t[5]  ={80,384,800,1120,1296};
constexpr int PBASE_t[5] ={0,20480,118784,323584,610304};

// runtime copies for k_red / k_inv
__constant__ int ROFFc[5]={0,16,64,144,256};
__constant__ int NMc[5]  ={1,3,5,7,9};
__constant__ int NTc[5]  ={5,8,10,10,9};
__constant__ int PSTRc[5]={80,384,800,1120,1296};
__constant__ int PBASEc[5]={0,20480,118784,323584,610304};

// ---------------- device globals ----------------
__device__ float  g_cgcD[NTRI][81];   // dense CG: slot = mi*n1 + p (host-filled)
__device__ float  g_vp[64*NCH];       // variance partials (non-atomic)
__device__ float  g_inv[NCH];
__device__ float2 g_part[PART_TOT];   // output partials (non-atomic)

// ------- kernel 1: variance pass — templated register CG, no ff array ---------
// grid (42, 64) = (triple, b-chunk of 4). 256 threads = channel (i,j).
template<int TR>
__device__ __forceinline__ void var_one(const float2* __restrict__ Fs, int bc, int t){
    constexpr int L=CT_L[TR], L1=CT_L1[TR], L2=CT_L2[TR], T=CT_T[TR];
    constexpr int N1=2*L1+1, N2=2*L2+1, NM=2*L+1;
    const int i=t>>4, j=t&15;
    const float* __restrict__ cg = g_cgcD[TR];
    float n2s=0.f;
    for(int b4=0;b4<4;b4++){
        const float2* FsB = Fs + (bc*4+b4)*400;
        float2 A[N1], Bv[N2];
        #pragma unroll
        for(int p=0;p<N1;p++) A[p]=FsB[ROFF_t[L1]+i*N1+p];
        #pragma unroll
        for(int q=0;q<N2;q++) Bv[q]=FsB[ROFF_t[L2]+j*N2+q];
        #pragma unroll
        for(int mi=0;mi<NM;mi++){
            float aR=0.f, aI=0.f;
            const int pLo = (mi-L+L1-L2) > 0 ? (mi-L+L1-L2) : 0;
            const int pHi = (mi-L+L1+L2) < 2*L1 ? (mi-L+L1+L2) : 2*L1;
            #pragma unroll
            for(int p=0;p<N1;p++){
                if(p>=pLo && p<=pHi){           // folds at compile time
                    const float c = cg[mi*N1+p];
                    const float2 a=A[p], bv=Bv[mi-L-p+L1+L2];
                    aR = fmaf(c, a.x*bv.x - a.y*bv.y, aR);
                    aI = fmaf(c, a.x*bv.y + a.y*bv.x, aI);
                }
            }
            n2s=fmaf(aR,aR,n2s); n2s=fmaf(aI,aI,n2s);
        }
    }
    g_vp[bc*NCH + GBASE_t[L] + T*256 + t] = n2s;
}

template<int TR>
__device__ __forceinline__ void var_disp(int tr, const float2* Fs, int bc, int t){
    if constexpr (TR < NTRI){
        if(tr==TR) var_one<TR>(Fs,bc,t);
        else       var_disp<TR+1>(tr,Fs,bc,t);
    }
}

__global__ void __launch_bounds__(256) k_var(const float2* __restrict__ Fs){
    var_disp<0>(blockIdx.x, Fs, blockIdx.y, threadIdx.x);
}

// ------- kernel 2: reduce variance partials -> inv scale ----------------------
__global__ void __launch_bounds__(256) k_inv(){
    const int c = blockIdx.x*256 + threadIdx.x;     // NCH = 42*256
    float s=0.f;
    for(int bc=0;bc<64;bc++) s += g_vp[bc*NCH + c];
    const int l = (c<1280)?0:(c<3328)?1:(c<5888)?2:(c<8448)?3:4;
    const float v = s/(256.0f*(float)(2*l+1));
    g_inv[c] = 1.0f/(sqrtf(v)+1e-5f);
}

// ------- kernel 3: fused CG + BN + matmul — R5 shape, non-atomic tail ---------
// grid (42, 256) = (triple, b). 256 threads.
template<int TR>
__device__ __forceinline__ void mm_one(const float2* __restrict__ Fs,
                                       const float2* __restrict__ W2,
                                       float2* __restrict__ sh, int b, int t){
    constexpr int L=CT_L[TR], L1=CT_L1[TR], L2=CT_L2[TR], T=CT_T[TR];
    constexpr int N1=2*L1+1, N2=2*L2+1, NM=2*L+1, K=KL_t[L];
    const float* __restrict__ cg = g_cgcD[TR];
    // phase A: thread = channel (i,j); write scaled CG product straight to LDS
    {
        const int i=t>>4, j=t&15;
        const float2* FsB = Fs + b*400;
        float2 A[N1], Bv[N2];
        #pragma unroll
        for(int p=0;p<N1;p++) A[p]=FsB[ROFF_t[L1]+i*N1+p];
        #pragma unroll
        for(int q=0;q<N2;q++) Bv[q]=FsB[ROFF_t[L2]+j*N2+q];
        const float invv = g_inv[GBASE_t[L]+T*256+t];
        #pragma unroll
        for(int mi=0;mi<NM;mi++){
            float aR=0.f, aI=0.f;
            const int pLo = (mi-L+L1-L2) > 0 ? (mi-L+L1-L2) : 0;
            const int pHi = (mi-L+L1+L2) < 2*L1 ? (mi-L+L1+L2) : 2*L1;
            #pragma unroll
            for(int p=0;p<N1;p++){
                if(p>=pLo && p<=pHi){
                    const float c = cg[mi*N1+p];
                    const float2 a=A[p], bv=Bv[mi-L-p+L1+L2];
                    aR = fmaf(c, a.x*bv.x - a.y*bv.y, aR);
                    aI = fmaf(c, a.x*bv.y + a.y*bv.x, aI);
                }
            }
            sh[mi*256+t]=make_float2(aR*invv, aI*invv);
        }
    }
    __syncthreads();
    // phase B: thread = (o=t>>4, sub=t&15); W loaded inside kk loop (VGPR-lean)
    const int o=t>>4, sub=t&15;
    const float2* __restrict__ Wrow = W2 + WOFF_t[L] + o*K + T*256;
    float2 acc[NM];
    #pragma unroll
    for(int m=0;m<NM;m++) acc[m]=make_float2(0.f,0.f);
    #pragma unroll
    for(int kk=0;kk<16;kk++){
        const int c2=(kk<<4)+sub;
        const float2 w = Wrow[c2];
        #pragma unroll
        for(int m=0;m<NM;m++){
            const float2 x=sh[m*256+c2];
            acc[m].x = fmaf(w.x,x.x, fmaf(-w.y,x.y, acc[m].x));
            acc[m].y = fmaf(w.x,x.y, fmaf( w.y,x.x, acc[m].y));
        }
    }
    // butterfly reduce over the 16 sub-lanes
    #pragma unroll
    for(int m=0;m<NM;m++){
        #pragma unroll
        for(int s=1;s<16;s<<=1){
            acc[m].x += __shfl_xor(acc[m].x,s,64);
            acc[m].y += __shfl_xor(acc[m].y,s,64);
        }
    }
    if(sub==0){
        float2* __restrict__ pp = g_part + PBASE_t[L] + b*PSTR_t[L] + T*(16*NM) + o*NM;
        #pragma unroll
        for(int m=0;m<NM;m++) pp[m]=acc[m];
    }
}

template<int TR>
__device__ __forceinline__ void mm_disp(int tr, const float2* Fs, const float2* W2,
                                        float2* sh, int b, int t){
    if constexpr (TR < NTRI){
        if(tr==TR) mm_one<TR>(Fs,W2,sh,b,t);
        else       mm_disp<TR+1>(tr,Fs,W2,sh,b,t);
    }
}

__global__ void __launch_bounds__(256) k_mm(const float2* __restrict__ Fs,
                                            const float2* __restrict__ W2){
    __shared__ float2 sh[9*256];
    mm_disp<0>(blockIdx.x, Fs, W2, sh, blockIdx.y, threadIdx.x);
}

// ------- kernel 4: reduce partials over tiles -> out --------------------------
__global__ void __launch_bounds__(448) k_red(float2* __restrict__ out){
    const int b=blockIdx.x, r=threadIdx.x;
    if(r>=400) return;
    const int l = (r<16)?0:(r<64)?1:(r<144)?2:(r<256)?3:4;
    const int om = r - ROFFc[l];            // == o*NM + m by row ordering
    const int nm=NMc[l], nt=NTc[l];
    const float2* pp = g_part + PBASEc[l] + b*PSTRc[l] + om;
    float2 s = make_float2(0.f,0.f);
    for(int T=0;T<nt;T++){
        float2 v = pp[T*16*nm];
        s.x += v.x; s.y += v.y;
    }
    out[b*400 + r] = s;
}

// ---------------- host-side CG table (identical every call; graph-safe) -------
static double h_fact(int n){ double r=1.0; for(int i=2;i<=n;i++) r*=(double)i; return r; }

static double h_cg_coef(int j1,int m1,int j2,int m2,int j,int m){
    if(m1+m2!=m) return 0.0;
    double pref = sqrt((2.0*j+1.0)*h_fact(j+j1-j2)*h_fact(j-j1+j2)*h_fact(j1+j2-j)/h_fact(j1+j2+j+1));
    pref *= sqrt(h_fact(j+m)*h_fact(j-m)*h_fact(j1-m1)*h_fact(j1+m1)*h_fact(j2-m2)*h_fact(j2+m2));
    double s=0.0;
    for(int k=0;k<=j1+j2-j;k++){
        int a=j1-m1-k, bb=j2+m2-k, c=j-j2+m1+k, dd=j-j1-m2+k;
        if(a<0||bb<0||c<0||dd<0) continue;
        double term = 1.0/(h_fact(k)*h_fact(j1+j2-j-k)*h_fact(a)*h_fact(bb)*h_fact(c)*h_fact(dd));
        s += (k&1)? -term : term;
    }
    return pref*s;
}

static float h_cgtab[NTRI][81];

static void build_cg_host(){
    for(int tr=0;tr<NTRI;tr++){
        const int l=CT_L[tr], l1=CT_L1[tr], l2=CT_L2[tr];
        const int nm=2*l+1, n1=2*l1+1;
        for(int s=0;s<81;s++) h_cgtab[tr][s]=0.f;
        for(int mi=0;mi<nm;mi++)
            for(int p=0;p<n1;p++){
                const int m=mi-l, m1=p-l1, m2=m-m1;
                if(m2>=-l2 && m2<=l2)
                    h_cgtab[tr][mi*n1+p]=(float)h_cg_coef(l1,m1,l2,m2,l,m);
            }
    }
}

// ---------------- launcher ----------------
extern "C" void kernel_launch(void* const* d_in, const int* in_sizes, int n_in,
                              void* d_out, int out_size, void* d_ws, size_t ws_size,
                              hipStream_t stream){
    const float2* Fs = (const float2*)d_in[0];   // [256,400,2] fp32
    const float2* W  = (const float2*)d_in[1];   // [172032,2]  fp32
    float2* out = (float2*)d_out;                // [256,400,2] fp32

    build_cg_host();                             // same values every call
    void* dcg=nullptr;
    hipGetSymbolAddress(&dcg, HIP_SYMBOL(g_cgcD));
    hipMemcpyAsync(dcg, h_cgtab, sizeof(h_cgtab), hipMemcpyHostToDevice, stream);

    k_var<<<dim3(NTRI,64),256,0,stream>>>(Fs);
    k_inv<<<dim3(NTRI),256,0,stream>>>();
    k_mm <<<dim3(NTRI,B_SZ),256,0,stream>>>(Fs,W);
    k_red<<<dim3(B_SZ),448,0,stream>>>(out);
}

// Round 11
// 161.127 us; speedup vs baseline: 1.5906x; 1.5906x over previous
//
#include <hip/hip_runtime.h>
#include <math.h>

// ---------------- static problem structure (LMAX=4, taus=16) ----------------
#define NTRI 42
#define NCH  10752
#define B_SZ 256
#define PART_TOT (NTRI*B_SZ*144)   // uniform partial layout, 12.4 MB

// triples sorted by (l,l1,l2); CT_T = tile index within degree l
constexpr int CT_L [NTRI]={0,0,0,0,0, 1,1,1,1,1,1,1,1, 2,2,2,2,2,2,2,2,2,2, 3,3,3,3,3,3,3,3,3,3, 4,4,4,4,4,4,4,4,4};
constexpr int CT_L1[NTRI]={0,1,2,3,4, 1,1,2,2,3,3,4,4, 1,2,2,2,3,3,3,4,4,4, 2,2,3,3,3,3,4,4,4,4, 2,3,3,3,4,4,4,4,4};
constexpr int CT_L2[NTRI]={0,1,2,3,4, 0,1,1,2,2,3,3,4, 1,0,1,2,1,2,3,2,3,4, 1,2,0,1,2,3,1,2,3,4, 2,1,2,3,0,1,2,3,4};
constexpr int CT_T [NTRI]={0,1,2,3,4, 0,1,2,3,4,5,6,7, 0,1,2,3,4,5,6,7,8,9, 0,1,2,3,4,5,6,7,8,9, 0,1,2,3,4,5,6,7,8};

constexpr int KL_t[5]    ={1280,2048,2560,2560,2304};   // t_FF[l]
constexpr int ROFF_t[5]  ={0,16,64,144,256};            // row offset in 400-row layout
constexpr int WOFF_t[5]  ={0,20480,53248,94208,135168}; // complex offset into W

// runtime tables for k_red
__constant__ int ROFFc[5]   ={0,16,64,144,256};
__constant__ int NMc[5]     ={1,3,5,7,9};
__constant__ int NTc[5]     ={5,8,10,10,9};
__constant__ int TRIBASEc[5]={0,5,13,23,33};

// ---------------- device globals ----------------
__device__ float  g_cgcD[NTRI][81];     // dense CG: slot = mi*n1 + p (host-filled)
__device__ float  g_vp[B_SZ*NCH];       // variance partials [b][gch], 11 MB
__device__ float  g_inv[NCH];
__device__ float2 g_part[PART_TOT];     // output partials [(tr*256+b)*144 + o*9 + m]

// ------- CG variance body: returns scalar (store hoisted out of branch) -------
template<int TR>
__device__ __forceinline__ float var_one(const float2* __restrict__ FsB, int t){
    constexpr int L=CT_L[TR], L1=CT_L1[TR], L2=CT_L2[TR];
    constexpr int N1=2*L1+1, N2=2*L2+1, NM=2*L+1;
    const int i=t>>4, j=t&15;
    const float* __restrict__ cg = g_cgcD[TR];
    float2 A[N1], Bv[N2];
    #pragma unroll
    for(int p=0;p<N1;p++) A[p]=FsB[ROFF_t[L1]+i*N1+p];
    #pragma unroll
    for(int q=0;q<N2;q++) Bv[q]=FsB[ROFF_t[L2]+j*N2+q];
    float n2s=0.f;
    #pragma unroll
    for(int mi=0;mi<NM;mi++){
        float aR=0.f, aI=0.f;
        const int pLo = (mi-L+L1-L2) > 0 ? (mi-L+L1-L2) : 0;
        const int pHi = (mi-L+L1+L2) < 2*L1 ? (mi-L+L1+L2) : 2*L1;
        #pragma unroll
        for(int p=0;p<N1;p++){
            if(p>=pLo && p<=pHi){               // folds at compile time
                const float c = cg[mi*N1+p];
                const float2 a=A[p], bv=Bv[mi-L-p+L1+L2];
                aR = fmaf(c, a.x*bv.x - a.y*bv.y, aR);
                aI = fmaf(c, a.x*bv.y + a.y*bv.x, aI);
            }
        }
        n2s=fmaf(aR,aR,n2s); n2s=fmaf(aI,aI,n2s);
    }
    return n2s;
}

template<int TR>
__device__ __forceinline__ float var_disp(int tr, const float2* FsB, int t){
    if constexpr (TR < NTRI){
        if(tr==TR) return var_one<TR>(FsB,t);
        else       return var_disp<TR+1>(tr,FsB,t);
    }
    return 0.f;
}

// grid: flat 42*256 (tr = g%42 interleaves l's). One b per block.
__global__ void __launch_bounds__(256) k_var(const float2* __restrict__ Fs){
    const int g=blockIdx.x, t=threadIdx.x;
    const int tr=g%NTRI, b=g/NTRI;
    const float n2s = var_disp<0>(tr, Fs + b*400, t);
    g_vp[b*NCH + tr*256 + t] = n2s;       // uniform, coalesced, non-atomic
}

// ------- kernel 2: reduce variance partials -> inv scale ----------------------
__global__ void __launch_bounds__(256) k_inv(){
    const int c = blockIdx.x*256 + threadIdx.x;     // NCH = 42*256
    float s=0.f;
    for(int b=0;b<B_SZ;b++) s += g_vp[b*NCH + c];   // coalesced across c
    const int l = (c<1280)?0:(c<3328)?1:(c<5888)?2:(c<8448)?3:4;
    const float v = s/(256.0f*(float)(2*l+1));
    g_inv[c] = 1.0f/(sqrtf(v)+1e-5f);
}

// ------- mm body: phase A -> LDS -> kk-loop into acc[0..NM). No stores. -------
template<int TR>
__device__ __forceinline__ void mm_one(const float2* __restrict__ FsB,
                                       const float2* __restrict__ W2,
                                       float2* __restrict__ sh,
                                       float invv, float2 (&acc)[9], int t){
    constexpr int L=CT_L[TR], L1=CT_L1[TR], L2=CT_L2[TR], T=CT_T[TR];
    constexpr int N1=2*L1+1, N2=2*L2+1, NM=2*L+1, K=KL_t[L];
    const float* __restrict__ cg = g_cgcD[TR];
    // phase A: thread = channel (i,j); scaled CG product straight to LDS
    {
        const int i=t>>4, j=t&15;
        float2 A[N1], Bv[N2];
        #pragma unroll
        for(int p=0;p<N1;p++) A[p]=FsB[ROFF_t[L1]+i*N1+p];
        #pragma unroll
        for(int q=0;q<N2;q++) Bv[q]=FsB[ROFF_t[L2]+j*N2+q];
        #pragma unroll
        for(int mi=0;mi<NM;mi++){
            float aR=0.f, aI=0.f;
            const int pLo = (mi-L+L1-L2) > 0 ? (mi-L+L1-L2) : 0;
            const int pHi = (mi-L+L1+L2) < 2*L1 ? (mi-L+L1+L2) : 2*L1;
            #pragma unroll
            for(int p=0;p<N1;p++){
                if(p>=pLo && p<=pHi){
                    const float c = cg[mi*N1+p];
                    const float2 a=A[p], bv=Bv[mi-L-p+L1+L2];
                    aR = fmaf(c, a.x*bv.x - a.y*bv.y, aR);
                    aI = fmaf(c, a.x*bv.y + a.y*bv.x, aI);
                }
            }
            sh[mi*256+t]=make_float2(aR*invv, aI*invv);
        }
    }
    __syncthreads();
    // phase B: thread = (o=t>>4, sub=t&15); W loaded in kk loop (VGPR-lean)
    const int o=t>>4, sub=t&15;
    const float2* __restrict__ Wrow = W2 + WOFF_t[L] + o*K + T*256;
    #pragma unroll
    for(int kk=0;kk<16;kk++){
        const int c2=(kk<<4)+sub;
        const float2 w = Wrow[c2];
        #pragma unroll
        for(int m=0;m<NM;m++){
            const float2 x=sh[m*256+c2];
            acc[m].x = fmaf(w.x,x.x, fmaf(-w.y,x.y, acc[m].x));
            acc[m].y = fmaf(w.x,x.y, fmaf( w.y,x.x, acc[m].y));
        }
    }
}

template<int TR>
__device__ __forceinline__ void mm_disp(int tr, const float2* FsB, const float2* W2,
                                        float2* sh, float invv, float2 (&acc)[9], int t){
    if constexpr (TR < NTRI){
        if(tr==TR) mm_one<TR>(FsB,W2,sh,invv,acc,t);
        else       mm_disp<TR+1>(tr,FsB,W2,sh,invv,acc,t);
    }
}

// grid: flat 42*256 (tr = g%42). Uniform butterfly+store tail OUTSIDE the chain.
__global__ void __launch_bounds__(256) k_mm(const float2* __restrict__ Fs,
                                            const float2* __restrict__ W2){
    __shared__ float2 sh[9*256];
    const int g=blockIdx.x, t=threadIdx.x;
    const int tr=g%NTRI, b=g/NTRI;
    const float invv = g_inv[tr*256 + t];           // uniform address
    float2 acc[9];
    #pragma unroll
    for(int m=0;m<9;m++) acc[m]=make_float2(0.f,0.f);
    mm_disp<0>(tr, Fs + b*400, W2, sh, invv, acc, t);
    // branch-uniform tail: butterfly all 9 slots, store all 9 (k_red reads nm)
    #pragma unroll
    for(int m=0;m<9;m++){
        #pragma unroll
        for(int s=1;s<16;s<<=1){
            acc[m].x += __shfl_xor(acc[m].x,s,64);
            acc[m].y += __shfl_xor(acc[m].y,s,64);
        }
    }
    const int o=t>>4, sub=t&15;
    if(sub==0){
        float2* __restrict__ pp = g_part + (tr*B_SZ + b)*144 + o*9;
        #pragma unroll
        for(int m=0;m<9;m++) pp[m]=acc[m];
    }
}

// ------- kernel 4: reduce partials over tiles -> out --------------------------
__global__ void __launch_bounds__(448) k_red(float2* __restrict__ out){
    const int b=blockIdx.x, r=threadIdx.x;
    if(r>=400) return;
    const int l = (r<16)?0:(r<64)?1:(r<144)?2:(r<256)?3:4;
    const int om = r - ROFFc[l];            // == o*nm + m by row ordering
    const int nm=NMc[l], nt=NTc[l], tb=TRIBASEc[l];
    const int o=om/nm, m=om-o*nm;
    float2 s = make_float2(0.f,0.f);
    for(int T=0;T<nt;T++){
        float2 v = g_part[((tb+T)*B_SZ + b)*144 + o*9 + m];
        s.x += v.x; s.y += v.y;
    }
    out[b*400 + r] = s;
}

// ---------------- host-side CG table (identical every call; graph-safe) -------
static double h_fact(int n){ double r=1.0; for(int i=2;i<=n;i++) r*=(double)i; return r; }

static double h_cg_coef(int j1,int m1,int j2,int m2,int j,int m){
    if(m1+m2!=m) return 0.0;
    double pref = sqrt((2.0*j+1.0)*h_fact(j+j1-j2)*h_fact(j-j1+j2)*h_fact(j1+j2-j)/h_fact(j1+j2+j+1));
    pref *= sqrt(h_fact(j+m)*h_fact(j-m)*h_fact(j1-m1)*h_fact(j1+m1)*h_fact(j2-m2)*h_fact(j2+m2));
    double s=0.0;
    for(int k=0;k<=j1+j2-j;k++){
        int a=j1-m1-k, bb=j2+m2-k, c=j-j2+m1+k, dd=j-j1-m2+k;
        if(a<0||bb<0||c<0||dd<0) continue;
        double term = 1.0/(h_fact(k)*h_fact(j1+j2-j-k)*h_fact(a)*h_fact(bb)*h_fact(c)*h_fact(dd));
        s += (k&1)? -term : term;
    }
    return pref*s;
}

static float h_cgtab[NTRI][81];

static void build_cg_host(){
    for(int tr=0;tr<NTRI;tr++){
        const int l=CT_L[tr], l1=CT_L1[tr], l2=CT_L2[tr];
        const int nm=2*l+1, n1=2*l1+1;
        for(int s=0;s<81;s++) h_cgtab[tr][s]=0.f;
        for(int mi=0;mi<nm;mi++)
            for(int p=0;p<n1;p++){
                const int m=mi-l, m1=p-l1, m2=m-m1;
                if(m2>=-l2 && m2<=l2)
                    h_cgtab[tr][mi*n1+p]=(float)h_cg_coef(l1,m1,l2,m2,l,m);
            }
    }
}

// ---------------- launcher ----------------
extern "C" void kernel_launch(void* const* d_in, const int* in_sizes, int n_in,
                              void* d_out, int out_size, void* d_ws, size_t ws_size,
                              hipStream_t stream){
    const float2* Fs = (const float2*)d_in[0];   // [256,400,2] fp32
    const float2* W  = (const float2*)d_in[1];   // [172032,2]  fp32
    float2* out = (float2*)d_out;                // [256,400,2] fp32

    build_cg_host();                             // same values every call
    void* dcg=nullptr;
    hipGetSymbolAddress(&dcg, HIP_SYMBOL(g_cgcD));
    hipMemcpyAsync(dcg, h_cgtab, sizeof(h_cgtab), hipMemcpyHostToDevice, stream);

    k_var<<<dim3(NTRI*B_SZ),256,0,stream>>>(Fs);
    k_inv<<<dim3(NTRI),256,0,stream>>>();
    k_mm <<<dim3(NTRI*B_SZ),256,0,stream>>>(Fs,W);
    k_red<<<dim3(B_SZ),448,0,stream>>>(out);
}

// Round 12
// 150.137 us; speedup vs baseline: 1.7071x; 1.0732x over previous
//
#include <hip/hip_runtime.h>
#include <math.h>

// ---------------- static problem structure (LMAX=4, taus=16) ----------------
#define NTRI 42
#define NCH  10752
#define B_SZ 256
#define NBC  32                     // variance b-chunks (8 b's each)
#define PART_TOT (NTRI*B_SZ*144)    // uniform partial layout, 12.4 MB

// triples sorted by (l,l1,l2); CT_T = tile index within degree l
constexpr int CT_L [NTRI]={0,0,0,0,0, 1,1,1,1,1,1,1,1, 2,2,2,2,2,2,2,2,2,2, 3,3,3,3,3,3,3,3,3,3, 4,4,4,4,4,4,4,4,4};
constexpr int CT_L1[NTRI]={0,1,2,3,4, 1,1,2,2,3,3,4,4, 1,2,2,2,3,3,3,4,4,4, 2,2,3,3,3,3,4,4,4,4, 2,3,3,3,4,4,4,4,4};
constexpr int CT_L2[NTRI]={0,1,2,3,4, 0,1,1,2,2,3,3,4, 1,0,1,2,1,2,3,2,3,4, 1,2,0,1,2,3,1,2,3,4, 2,1,2,3,0,1,2,3,4};
constexpr int CT_T [NTRI]={0,1,2,3,4, 0,1,2,3,4,5,6,7, 0,1,2,3,4,5,6,7,8,9, 0,1,2,3,4,5,6,7,8,9, 0,1,2,3,4,5,6,7,8};

constexpr int KL_t[5]    ={1280,2048,2560,2560,2304};   // t_FF[l]
constexpr int ROFF_t[5]  ={0,16,64,144,256};            // row offset in 400-row layout
constexpr int WOFF_t[5]  ={0,20480,53248,94208,135168}; // complex offset into W

// runtime tables for k_red
__constant__ int ROFFc[5]   ={0,16,64,144,256};
__constant__ int NMc[5]     ={1,3,5,7,9};
__constant__ int NTc[5]     ={5,8,10,10,9};
__constant__ int TRIBASEc[5]={0,5,13,23,33};

// ---------------- device globals ----------------
__device__ float  g_cgcD[NTRI][81];     // dense CG: slot = mi*n1 + p (host-filled)
__device__ float  g_vp[NBC*NCH];        // variance partials [bc][gch], 1.4 MB
__device__ float  g_inv[NCH];
__device__ float2 g_part[PART_TOT];     // output partials [(tr*256+b)*144 + o*9 + m]

// ------- CG variance body: 8 b's summed in-register, returns scalar -----------
template<int TR>
__device__ __forceinline__ float var_one(const float2* __restrict__ Fs, int bc, int t){
    constexpr int L=CT_L[TR], L1=CT_L1[TR], L2=CT_L2[TR];
    constexpr int N1=2*L1+1, N2=2*L2+1, NM=2*L+1;
    const int i=t>>4, j=t&15;
    const float* __restrict__ cg = g_cgcD[TR];
    float n2s=0.f;
    for(int b8=0;b8<8;b8++){
        const float2* FsB = Fs + (bc*8+b8)*400;
        float2 A[N1], Bv[N2];
        #pragma unroll
        for(int p=0;p<N1;p++) A[p]=FsB[ROFF_t[L1]+i*N1+p];
        #pragma unroll
        for(int q=0;q<N2;q++) Bv[q]=FsB[ROFF_t[L2]+j*N2+q];
        #pragma unroll
        for(int mi=0;mi<NM;mi++){
            float aR=0.f, aI=0.f;
            const int pLo = (mi-L+L1-L2) > 0 ? (mi-L+L1-L2) : 0;
            const int pHi = (mi-L+L1+L2) < 2*L1 ? (mi-L+L1+L2) : 2*L1;
            #pragma unroll
            for(int p=0;p<N1;p++){
                if(p>=pLo && p<=pHi){               // folds at compile time
                    const float c = cg[mi*N1+p];
                    const float2 a=A[p], bv=Bv[mi-L-p+L1+L2];
                    aR = fmaf(c, a.x*bv.x - a.y*bv.y, aR);
                    aI = fmaf(c, a.x*bv.y + a.y*bv.x, aI);
                }
            }
            n2s=fmaf(aR,aR,n2s); n2s=fmaf(aI,aI,n2s);
        }
    }
    return n2s;
}

template<int TR>
__device__ __forceinline__ float var_disp(int tr, const float2* Fs, int bc, int t){
    if constexpr (TR < NTRI){
        if(tr==TR) return var_one<TR>(Fs,bc,t);
        else       return var_disp<TR+1>(tr,Fs,bc,t);
    }
    return 0.f;
}

// grid: flat 42*32 (tr = g%42 interleaves l's). 8 b's per block.
__global__ void __launch_bounds__(256) k_var(const float2* __restrict__ Fs){
    const int g=blockIdx.x, t=threadIdx.x;
    const int tr=g%NTRI, bc=g/NTRI;
    const float n2s = var_disp<0>(tr, Fs, bc, t);
    g_vp[bc*NCH + tr*256 + t] = n2s;       // uniform, coalesced, non-atomic
}

// ------- kernel 2: reduce variance partials -> inv scale ----------------------
__global__ void __launch_bounds__(256) k_inv(){
    const int c = blockIdx.x*256 + threadIdx.x;     // NCH = 42*256
    float s=0.f;
    for(int bc=0;bc<NBC;bc++) s += g_vp[bc*NCH + c];
    const int l = (c<1280)?0:(c<3328)?1:(c<5888)?2:(c<8448)?3:4;
    const float v = s/(256.0f*(float)(2*l+1));
    g_inv[c] = 1.0f/(sqrtf(v)+1e-5f);
}

// ------- mm body: phase A -> LDS -> kk-loop -> NM-slot butterfly. No stores. --
template<int TR>
__device__ __forceinline__ void mm_one(const float2* __restrict__ FsB,
                                       const float2* __restrict__ W2,
                                       float2* __restrict__ sh,
                                       float invv, float2 (&acc)[9], int t){
    constexpr int L=CT_L[TR], L1=CT_L1[TR], L2=CT_L2[TR], T=CT_T[TR];
    constexpr int N1=2*L1+1, N2=2*L2+1, NM=2*L+1, K=KL_t[L];
    const float* __restrict__ cg = g_cgcD[TR];
    // phase A: thread = channel (i,j); scaled CG product straight to LDS
    {
        const int i=t>>4, j=t&15;
        float2 A[N1], Bv[N2];
        #pragma unroll
        for(int p=0;p<N1;p++) A[p]=FsB[ROFF_t[L1]+i*N1+p];
        #pragma unroll
        for(int q=0;q<N2;q++) Bv[q]=FsB[ROFF_t[L2]+j*N2+q];
        #pragma unroll
        for(int mi=0;mi<NM;mi++){
            float aR=0.f, aI=0.f;
            const int pLo = (mi-L+L1-L2) > 0 ? (mi-L+L1-L2) : 0;
            const int pHi = (mi-L+L1+L2) < 2*L1 ? (mi-L+L1+L2) : 2*L1;
            #pragma unroll
            for(int p=0;p<N1;p++){
                if(p>=pLo && p<=pHi){
                    const float c = cg[mi*N1+p];
                    const float2 a=A[p], bv=Bv[mi-L-p+L1+L2];
                    aR = fmaf(c, a.x*bv.x - a.y*bv.y, aR);
                    aI = fmaf(c, a.x*bv.y + a.y*bv.x, aI);
                }
            }
            sh[mi*256+t]=make_float2(aR*invv, aI*invv);
        }
    }
    __syncthreads();
    // phase B: thread = (o=t>>4, sub=t&15); W loaded in kk loop (VGPR-lean)
    const int o=t>>4, sub=t&15;
    const float2* __restrict__ Wrow = W2 + WOFF_t[L] + o*K + T*256;
    #pragma unroll
    for(int kk=0;kk<16;kk++){
        const int c2=(kk<<4)+sub;
        const float2 w = Wrow[c2];
        #pragma unroll
        for(int m=0;m<NM;m++){
            const float2 x=sh[m*256+c2];
            acc[m].x = fmaf(w.x,x.x, fmaf(-w.y,x.y, acc[m].x));
            acc[m].y = fmaf(w.x,x.y, fmaf( w.y,x.x, acc[m].y));
        }
    }
    // butterfly only the NM live slots (shfl in-branch is VGPR-safe: R5 evidence)
    #pragma unroll
    for(int m=0;m<NM;m++){
        #pragma unroll
        for(int s=1;s<16;s<<=1){
            acc[m].x += __shfl_xor(acc[m].x,s,64);
            acc[m].y += __shfl_xor(acc[m].y,s,64);
        }
    }
}

template<int TR>
__device__ __forceinline__ void mm_disp(int tr, const float2* FsB, const float2* W2,
                                        float2* sh, float invv, float2 (&acc)[9], int t){
    if constexpr (TR < NTRI){
        if(tr==TR) mm_one<TR>(FsB,W2,sh,invv,acc,t);
        else       mm_disp<TR+1>(tr,FsB,W2,sh,invv,acc,t);
    }
}

// grid: flat 42*256 (tr = g%42). Uniform store tail OUTSIDE the chain.
__global__ void __launch_bounds__(256) k_mm(const float2* __restrict__ Fs,
                                            const float2* __restrict__ W2){
    __shared__ float2 sh[9*256];
    const int g=blockIdx.x, t=threadIdx.x;
    const int tr=g%NTRI, b=g/NTRI;
    const float invv = g_inv[tr*256 + t];           // uniform address
    float2 acc[9];
    #pragma unroll
    for(int m=0;m<9;m++) acc[m]=make_float2(0.f,0.f);
    mm_disp<0>(tr, Fs + b*400, W2, sh, invv, acc, t);
    const int o=t>>4, sub=t&15;
    if(sub==0){
        float2* __restrict__ pp = g_part + (tr*B_SZ + b)*144 + o*9;
        #pragma unroll
        for(int m=0;m<9;m++) pp[m]=acc[m];          // slots >= NM hold zeros
    }
}

// ------- kernel 4: reduce partials over tiles -> out --------------------------
__global__ void __launch_bounds__(448) k_red(float2* __restrict__ out){
    const int b=blockIdx.x, r=threadIdx.x;
    if(r>=400) return;
    const int l = (r<16)?0:(r<64)?1:(r<144)?2:(r<256)?3:4;
    const int om = r - ROFFc[l];            // == o*nm + m by row ordering
    const int nm=NMc[l], nt=NTc[l], tb=TRIBASEc[l];
    const int o=om/nm, m=om-o*nm;
    float2 s = make_float2(0.f,0.f);
    for(int T=0;T<nt;T++){
        float2 v = g_part[((tb+T)*B_SZ + b)*144 + o*9 + m];
        s.x += v.x; s.y += v.y;
    }
    out[b*400 + r] = s;
}

// ---------------- host-side CG table (identical every call; graph-safe) -------
static double h_fact(int n){ double r=1.0; for(int i=2;i<=n;i++) r*=(double)i; return r; }

static double h_cg_coef(int j1,int m1,int j2,int m2,int j,int m){
    if(m1+m2!=m) return 0.0;
    double pref = sqrt((2.0*j+1.0)*h_fact(j+j1-j2)*h_fact(j-j1+j2)*h_fact(j1+j2-j)/h_fact(j1+j2+j+1));
    pref *= sqrt(h_fact(j+m)*h_fact(j-m)*h_fact(j1-m1)*h_fact(j1+m1)*h_fact(j2-m2)*h_fact(j2+m2));
    double s=0.0;
    for(int k=0;k<=j1+j2-j;k++){
        int a=j1-m1-k, bb=j2+m2-k, c=j-j2+m1+k, dd=j-j1-m2+k;
        if(a<0||bb<0||c<0||dd<0) continue;
        double term = 1.0/(h_fact(k)*h_fact(j1+j2-j-k)*h_fact(a)*h_fact(bb)*h_fact(c)*h_fact(dd));
        s += (k&1)? -term : term;
    }
    return pref*s;
}

static float h_cgtab[NTRI][81];

static void build_cg_host(){
    for(int tr=0;tr<NTRI;tr++){
        const int l=CT_L[tr], l1=CT_L1[tr], l2=CT_L2[tr];
        const int nm=2*l+1, n1=2*l1+1;
        for(int s=0;s<81;s++) h_cgtab[tr][s]=0.f;
        for(int mi=0;mi<nm;mi++)
            for(int p=0;p<n1;p++){
                const int m=mi-l, m1=p-l1, m2=m-m1;
                if(m2>=-l2 && m2<=l2)
                    h_cgtab[tr][mi*n1+p]=(float)h_cg_coef(l1,m1,l2,m2,l,m);
            }
    }
}

// ---------------- launcher ----------------
extern "C" void kernel_launch(void* const* d_in, const int* in_sizes, int n_in,
                              void* d_out, int out_size, void* d_ws, size_t ws_size,
                              hipStream_t stream){
    const float2* Fs = (const float2*)d_in[0];   // [256,400,2] fp32
    const float2* W  = (const float2*)d_in[1];   // [172032,2]  fp32
    float2* out = (float2*)d_out;                // [256,400,2] fp32

    build_cg_host();                             // same values every call
    void* dcg=nullptr;
    hipGetSymbolAddress(&dcg, HIP_SYMBOL(g_cgcD));
    hipMemcpyAsync(dcg, h_cgtab, sizeof(h_cgtab), hipMemcpyHostToDevice, stream);

    k_var<<<dim3(NTRI*NBC),256,0,stream>>>(Fs);
    k_inv<<<dim3(NTRI),256,0,stream>>>();
    k_mm <<<dim3(NTRI*B_SZ),256,0,stream>>>(Fs,W);
    k_red<<<dim3(B_SZ),448,0,stream>>>(out);
}